// Round 12
// baseline (949.493 us; speedup 1.0000x reference)
//
#include <hip/hip_runtime.h>
#include <hip/hip_bf16.h>

#define NFEAT 256

typedef __attribute__((ext_vector_type(8))) short bf16x8;   // MFMA A/B frag (4 VGPRs)
typedef __attribute__((ext_vector_type(4))) float f32x4;    // MFMA C/D frag
typedef __attribute__((ext_vector_type(8))) unsigned short us8;

__device__ __forceinline__ void f2hilo(float x, unsigned short& h, unsigned short& l) {
    __hip_bfloat16 hb = __float2bfloat16(x);          // RNE
    float hf = __bfloat162float(hb);
    __hip_bfloat16 lb = __float2bfloat16(x - hf);
    h = *reinterpret_cast<unsigned short*>(&hb);
    l = *reinterpret_cast<unsigned short*>(&lb);
}

__device__ __forceinline__ void load_a16(const float* __restrict__ p, float* af) {
    float4 u0 = ((const float4*)p)[0];
    float4 u1 = ((const float4*)p)[1];
    float4 u2 = ((const float4*)p)[2];
    float4 u3 = ((const float4*)p)[3];
    af[0]=u0.x; af[1]=u0.y; af[2]=u0.z; af[3]=u0.w;
    af[4]=u1.x; af[5]=u1.y; af[6]=u1.z; af[7]=u1.w;
    af[8]=u2.x; af[9]=u2.y; af[10]=u2.z; af[11]=u2.w;
    af[12]=u3.x; af[13]=u3.y; af[14]=u3.z; af[15]=u3.w;
}

__device__ __forceinline__ void load_b(const unsigned short* __restrict__ ph,
                                       const unsigned short* __restrict__ pl, us8* bb) {
    bb[0] = *(const us8*)ph;
    bb[1] = *(const us8*)(ph + 8);
    bb[2] = *(const us8*)pl;
    bb[3] = *(const us8*)(pl + 8);
}

// ---------------- weight conversion (pre-swizzled fragment-major planes) ----------------
// element W[k][c] -> plane[ ((c>>7)*8 + (k>>5))*4096 + (c&127)*32 + (k&31) ]
__global__ __launch_bounds__(256) void cvt8_kernel(
    const float* w0, const float* w1, const float* w2, const float* w3,
    const float* w4, const float* w5, const float* w6, const float* w7,
    unsigned short* base)
{
    int wi = blockIdx.y;
    const float* W = (wi==0)?w0:(wi==1)?w1:(wi==2)?w2:(wi==3)?w3:
                     (wi==4)?w4:(wi==5)?w5:(wi==6)?w6:w7;
    int idx = blockIdx.x * 256 + threadIdx.x;     // 0..65535
    int k = idx >> 8, c = idx & 255;
    unsigned short h, l;
    f2hilo(W[idx], h, l);
    size_t dst = ((size_t)((c >> 7) * 8 + (k >> 5)) * 128 + (c & 127)) * 32 + (k & 31);
    unsigned short* Th = base + (size_t)wi * 131072;
    Th[dst] = h;
    Th[65536 + dst] = l;
}

__global__ __launch_bounds__(256) void cvtfold_kernel(
    const float* a0, const float* a1, const float* a2,
    const float* b0, const float* b1, const float* b2,
    unsigned short* base)
{
    int wi = blockIdx.y;
    int idx = blockIdx.x * 256 + threadIdx.x;
    float v = wi ? (b0[idx] + b1[idx] + b2[idx]) : (a0[idx] + a1[idx] + a2[idx]);
    int k = idx >> 8, c = idx & 255;
    unsigned short h, l;
    f2hilo(v, h, l);
    size_t dst = ((size_t)((c >> 7) * 8 + (k >> 5)) * 128 + (c & 127)) * 32 + (k & 31);
    unsigned short* Th = base + (size_t)(8 + wi) * 131072;
    Th[dst] = h;
    Th[65536 + dst] = l;
}

__global__ __launch_bounds__(256) void cvtrect_kernel(const float* W, unsigned short* base) {
    int idx = blockIdx.x * 256 + threadIdx.x;     // 0..32767
    if (idx >= 256 * 128) return;
    int k = idx >> 7, c = idx & 127;
    unsigned short h, l;
    f2hilo(W[idx], h, l);
    size_t dst = ((size_t)(k >> 5) * 128 + c) * 32 + (k & 31);
    unsigned short* Th = base + (size_t)10 * 131072;
    Th[dst] = h;
    Th[65536 + dst] = l;
}

// ---------------- CSR build ----------------
__global__ __launch_bounds__(256) void deg_int_kernel(const int* __restrict__ dst,
                                                      int* __restrict__ deg, int nE) {
    int e = blockIdx.x * 256 + threadIdx.x;
    if (e < nE) atomicAdd(&deg[dst[e]], 1);
}

__global__ __launch_bounds__(256) void scan_p1(const int* __restrict__ deg, int n,
                                               int* __restrict__ off, int* __restrict__ bsum) {
    __shared__ int tmp[256];
    int tid = threadIdx.x;
    int i = blockIdx.x * 256 + tid;
    tmp[tid] = (i < n) ? deg[i] : 0;
    __syncthreads();
    #pragma unroll
    for (int ofs = 1; ofs < 256; ofs <<= 1) {
        int t = (tid >= ofs) ? tmp[tid - ofs] : 0;
        __syncthreads();
        tmp[tid] += t;
        __syncthreads();
    }
    if (i < n) off[i + 1] = tmp[tid];
    if (tid == 255) bsum[blockIdx.x] = tmp[255];
}

__global__ __launch_bounds__(256) void scan_p2(int* __restrict__ bA, int nA,
                                               int* __restrict__ bB, int nB,
                                               int* __restrict__ bC, int nC) {
    int* bs; int nb;
    if (blockIdx.x == 0) { bs = bA; nb = nA; }
    else if (blockIdx.x == 1) { bs = bB; nb = nB; }
    else { bs = bC; nb = nC; }
    __shared__ int tmp[256];
    int tid = threadIdx.x;
    tmp[tid] = (tid < nb) ? bs[tid] : 0;
    __syncthreads();
    #pragma unroll
    for (int ofs = 1; ofs < 256; ofs <<= 1) {
        int t = (tid >= ofs) ? tmp[tid - ofs] : 0;
        __syncthreads();
        tmp[tid] += t;
        __syncthreads();
    }
    if (tid < nb) bs[tid] = tmp[tid];
}

__global__ __launch_bounds__(256) void scan_p3(int n, int* __restrict__ off,
                                               const int* __restrict__ bsum) {
    int i = blockIdx.x * 256 + threadIdx.x;
    if (i == 0) off[0] = 0;
    if (i >= n) return;
    int b = blockIdx.x;
    if (b > 0) off[i + 1] += bsum[b - 1];
}

__global__ __launch_bounds__(256) void fill_csr_kernel(const int* __restrict__ src,
                                                       const int* __restrict__ dst, int nE,
                                                       const int* __restrict__ off,
                                                       int* __restrict__ cursor,
                                                       int* __restrict__ list) {
    int e = blockIdx.x * 256 + threadIdx.x;
    if (e >= nE) return;
    int d = dst[e];
    int pos = atomicAdd(&cursor[d], 1);
    list[off[d] + pos] = src[e];
}

// ---------------- aggregation (gather, no atomics) ----------------
__global__ __launch_bounds__(256) void agg_csr_kernel(const float* __restrict__ T,
                                                      const int* __restrict__ off,
                                                      const int* __restrict__ list,
                                                      float* __restrict__ D,
                                                      int mode_add, int do_relu, int M) {
    int r = blockIdx.x * 4 + (threadIdx.x >> 6);
    if (r >= M) return;
    int lane = threadIdx.x & 63;
    int start = off[r], end = off[r + 1];
    float4 acc = make_float4(0.f, 0.f, 0.f, 0.f);
    for (int e = start; e < end; ++e) {
        int s = list[e];
        float4 v = ((const float4*)(T + (size_t)s * NFEAT))[lane];
        acc.x += v.x; acc.y += v.y; acc.z += v.z; acc.w += v.w;
    }
    int cnt = end - start;
    float inv = (cnt > 0) ? 1.0f / (float)cnt : 0.0f;
    float4 d;
    if (mode_add) {
        d = ((float4*)(D + (size_t)r * NFEAT))[lane];
        d.x += acc.x * inv; d.y += acc.y * inv;
        d.z += acc.z * inv; d.w += acc.w * inv;
    } else {
        d.x = acc.x * inv; d.y = acc.y * inv;
        d.z = acc.z * inv; d.w = acc.w * inv;
    }
    if (do_relu) {
        d.x = fmaxf(d.x, 0.f); d.y = fmaxf(d.y, 0.f);
        d.z = fmaxf(d.z, 0.f); d.w = fmaxf(d.w, 0.f);
    }
    ((float4*)(D + (size_t)r * NFEAT))[lane] = d;
}

// ---------------- alpha ----------------
__global__ __launch_bounds__(256) void alpha_kernel(const float* __restrict__ s0,
                                                    const float* __restrict__ s1,
                                                    float* __restrict__ alpha, int M) {
    int n = blockIdx.x * 256 + threadIdx.x;
    if (n >= M) return;
    float v0 = s0[n], v1 = s1[n];
    float m = fmaxf(v0, v1);
    float e0 = expf(v0 - m), e1 = expf(v1 - m);
    float inv = 1.0f / (e0 + e1);
    alpha[n]     = e0 * inv;
    alpha[M + n] = e1 * inv;
}

// ---------------- multi-segment split-bf16 MFMA GEMM ----------------
// Fragment-major A+B LDS (conflict-free) + 1-iter register prefetch.
struct Seg3 {
    const float *A0, *A1, *A2;
    const unsigned short *Wh0, *Wl0, *Wh1, *Wl1, *Wh2, *Wl2;
};

__global__ __launch_bounds__(256, 2) void gemm_ms(
    Seg3 sp, int nseg, const float* __restrict__ bias, int do_relu,
    float* __restrict__ C, int M, int N)
{
    __shared__ unsigned short Ah[128 * 32];   // 8 KB each, fragment-major granules
    __shared__ unsigned short Al[128 * 32];
    __shared__ unsigned short Bh[128 * 32];
    __shared__ unsigned short Bl[128 * 32];

    int tid = threadIdx.x;
    int lane = tid & 63;
    int w = tid >> 6;
    int wr = w >> 1, wc = w & 1;
    int rb = blockIdx.x >> 1, cb = blockIdx.x & 1;   // colblock inner for L2 A-reuse
    int row0 = rb * 128, col0 = cb * 128;
    int fr = lane & 15;
    int fg = lane >> 4;

    int sr = tid & 127;          // A staging row
    int sh = tid >> 7;           // A k-half (16 elems)
    int grow = row0 + sr; if (grow >= M) grow = M - 1;
    int wbase = (((sr >> 4) * 64) + (sh * 2) * 16 + (sr & 15)) * 8;

    int bc = tid >> 1;           // B staging col
    int bk = (tid & 1) * 16;     // B k offset
    int bbase = (((bc >> 4) * 64) + (tid & 1) * 2 * 16 + (bc & 15)) * 8;

    f32x4 acc[4][4];
    #pragma unroll
    for (int m = 0; m < 4; ++m)
        #pragma unroll
        for (int n = 0; n < 4; ++n)
            acc[m][n] = (f32x4)(0.f);

    int niters = nseg * 8;
    float af[16];
    us8 bb[4];
    // prologue: load it=0
    load_a16(sp.A0 + (size_t)grow * NFEAT + sh * 16, af);
    load_b(sp.Wh0 + (size_t)(cb * 8) * 4096 + bc * 32 + bk,
           sp.Wl0 + (size_t)(cb * 8) * 4096 + bc * 32 + bk, bb);

    for (int it = 0; it < niters; ++it) {
        unsigned short hh[16], ll[16];
        #pragma unroll
        for (int j = 0; j < 16; ++j) f2hilo(af[j], hh[j], ll[j]);
        __syncthreads();
        *(us8*)&Ah[wbase]       = *(us8*)&hh[0];
        *(us8*)&Ah[wbase + 128] = *(us8*)&hh[8];
        *(us8*)&Al[wbase]       = *(us8*)&ll[0];
        *(us8*)&Al[wbase + 128] = *(us8*)&ll[8];
        *(us8*)&Bh[bbase]       = bb[0];
        *(us8*)&Bh[bbase + 128] = bb[1];
        *(us8*)&Bl[bbase]       = bb[2];
        *(us8*)&Bl[bbase + 128] = bb[3];
        __syncthreads();

        if (it + 1 < niters) {   // prefetch next iter; flies under the MFMA cluster
            int s = (it + 1) >> 3, kq = (it + 1) & 7;
            const float* A = (s == 0) ? sp.A0 : (s == 1) ? sp.A1 : sp.A2;
            const unsigned short* Wh = (s == 0) ? sp.Wh0 : (s == 1) ? sp.Wh1 : sp.Wh2;
            const unsigned short* Wl = (s == 0) ? sp.Wl0 : (s == 1) ? sp.Wl1 : sp.Wl2;
            load_a16(A + (size_t)grow * NFEAT + kq * 32 + sh * 16, af);
            load_b(Wh + (size_t)(cb * 8 + kq) * 4096 + bc * 32 + bk,
                   Wl + (size_t)(cb * 8 + kq) * 4096 + bc * 32 + bk, bb);
        }

        bf16x8 ahf[4], alf[4], bhf[4], blf[4];
        #pragma unroll
        for (int m = 0; m < 4; ++m) {
            int g = ((wr * 4 + m) * 64 + lane) * 8;
            ahf[m] = *(const bf16x8*)&Ah[g];
            alf[m] = *(const bf16x8*)&Al[g];
        }
        #pragma unroll
        for (int n = 0; n < 4; ++n) {
            int g = ((wc * 4 + n) * 64 + lane) * 8;
            bhf[n] = *(const bf16x8*)&Bh[g];
            blf[n] = *(const bf16x8*)&Bl[g];
        }
        #pragma unroll
        for (int m = 0; m < 4; ++m)
            #pragma unroll
            for (int n = 0; n < 4; ++n) {
                acc[m][n] = __builtin_amdgcn_mfma_f32_16x16x32_bf16(ahf[m], bhf[n], acc[m][n], 0, 0, 0);
                acc[m][n] = __builtin_amdgcn_mfma_f32_16x16x32_bf16(alf[m], bhf[n], acc[m][n], 0, 0, 0);
                acc[m][n] = __builtin_amdgcn_mfma_f32_16x16x32_bf16(ahf[m], blf[n], acc[m][n], 0, 0, 0);
            }
    }

    #pragma unroll
    for (int n = 0; n < 4; ++n) {
        int c = col0 + wc * 64 + n * 16 + fr;
        float bv = bias ? bias[c] : 0.f;
        #pragma unroll
        for (int m = 0; m < 4; ++m) {
            int rbase = row0 + wr * 64 + m * 16 + fg * 4;
            #pragma unroll
            for (int i = 0; i < 4; ++i) {
                int r = rbase + i;
                if (r < M) {
                    float v = acc[m][n][i] + bv;
                    if (do_relu) v = fmaxf(v, 0.f);
                    C[(size_t)r * N + c] = v;
                }
            }
        }
    }
}

// ---------------- twin L1 + both rowdots, fused ----------------
// s1[r] = dot( relu(X[r]@W + bias), P[r] );  s0[r] = dot(X[r], Q[r])
__global__ __launch_bounds__(256, 2) void gemm_rowdot_mfma(
    const float* __restrict__ X,
    const unsigned short* __restrict__ Wh, const unsigned short* __restrict__ Wl,
    const float* __restrict__ bias,
    const float* __restrict__ P, const float* __restrict__ Q,
    float* __restrict__ s0g, float* __restrict__ s1g, int M)
{
    __shared__ unsigned short Ah[128 * 32];
    __shared__ unsigned short Al[128 * 32];
    __shared__ unsigned short Bh[128 * 32];
    __shared__ unsigned short Bl[128 * 32];
    __shared__ float srow[128];
    __shared__ float s0buf[256];

    int tid = threadIdx.x;
    int lane = tid & 63;
    int w = tid >> 6;
    int wr = w >> 1, wc = w & 1;
    int row0 = blockIdx.x * 128;
    int fr = lane & 15;
    int fg = lane >> 4;

    int sr = tid & 127;
    int sh = tid >> 7;
    int grow = row0 + sr; if (grow >= M) grow = M - 1;
    int wbase = (((sr >> 4) * 64) + (sh * 2) * 16 + (sr & 15)) * 8;
    int bc = tid >> 1;
    int bk = (tid & 1) * 16;
    int bbase = (((bc >> 4) * 64) + (tid & 1) * 2 * 16 + (bc & 15)) * 8;

    if (tid < 128) srow[tid] = 0.f;
    float s0part = 0.f;

    const float* Xrow = X + (size_t)grow * NFEAT + sh * 16;
    const float* Qrow = Q + (size_t)grow * NFEAT + sh * 16;

    float rp[4][4];
    #pragma unroll
    for (int m = 0; m < 4; ++m)
        #pragma unroll
        for (int i = 0; i < 4; ++i) rp[m][i] = 0.f;

    f32x4 acc[4][4];
    #pragma unroll
    for (int m = 0; m < 4; ++m)
        #pragma unroll
        for (int n = 0; n < 4; ++n)
            acc[m][n] = (f32x4)(0.f);

    float af[16], qf[16];
    us8 bb[4];
    load_a16(Xrow, af);
    load_a16(Qrow, qf);
    load_b(Wh + bc * 32 + bk, Wl + bc * 32 + bk, bb);

    for (int it = 0; it < 16; ++it) {           // it = ct*8 + kq
        if (it < 8) {
            #pragma unroll
            for (int j = 0; j < 16; ++j) s0part += af[j] * qf[j];
        }
        unsigned short hh[16], ll[16];
        #pragma unroll
        for (int j = 0; j < 16; ++j) f2hilo(af[j], hh[j], ll[j]);
        __syncthreads();
        *(us8*)&Ah[wbase]       = *(us8*)&hh[0];
        *(us8*)&Ah[wbase + 128] = *(us8*)&hh[8];
        *(us8*)&Al[wbase]       = *(us8*)&ll[0];
        *(us8*)&Al[wbase + 128] = *(us8*)&ll[8];
        *(us8*)&Bh[bbase]       = bb[0];
        *(us8*)&Bh[bbase + 128] = bb[1];
        *(us8*)&Bl[bbase]       = bb[2];
        *(us8*)&Bl[bbase + 128] = bb[3];
        __syncthreads();

        if (it + 1 < 16) {
            int kq = (it + 1) & 7;
            load_a16(Xrow + kq * 32, af);
            if (it + 1 < 8) load_a16(Qrow + kq * 32, qf);
            load_b(Wh + (size_t)(it + 1) * 4096 + bc * 32 + bk,
                   Wl + (size_t)(it + 1) * 4096 + bc * 32 + bk, bb);
        }

        bf16x8 ahf[4], alf[4], bhf[4], blf[4];
        #pragma unroll
        for (int m = 0; m < 4; ++m) {
            int g = ((wr * 4 + m) * 64 + lane) * 8;
            ahf[m] = *(const bf16x8*)&Ah[g];
            alf[m] = *(const bf16x8*)&Al[g];
        }
        #pragma unroll
        for (int n = 0; n < 4; ++n) {
            int g = ((wc * 4 + n) * 64 + lane) * 8;
            bhf[n] = *(const bf16x8*)&Bh[g];
            blf[n] = *(const bf16x8*)&Bl[g];
        }
        #pragma unroll
        for (int m = 0; m < 4; ++m)
            #pragma unroll
            for (int n = 0; n < 4; ++n) {
                acc[m][n] = __builtin_amdgcn_mfma_f32_16x16x32_bf16(ahf[m], bhf[n], acc[m][n], 0, 0, 0);
                acc[m][n] = __builtin_amdgcn_mfma_f32_16x16x32_bf16(alf[m], bhf[n], acc[m][n], 0, 0, 0);
                acc[m][n] = __builtin_amdgcn_mfma_f32_16x16x32_bf16(ahf[m], blf[n], acc[m][n], 0, 0, 0);
            }

        if ((it & 7) == 7) {    // fold finished colblock into row dots, reset acc
            int col0 = (it >> 3) * 128;
            #pragma unroll
            for (int n = 0; n < 4; ++n) {
                int c = col0 + wc * 64 + n * 16 + fr;
                float bv = bias[c];
                #pragma unroll
                for (int m = 0; m < 4; ++m) {
                    #pragma unroll
                    for (int i = 0; i < 4; ++i) {
                        int r = row0 + wr * 64 + m * 16 + fg * 4 + i;
                        if (r < M) {
                            float v = fmaxf(acc[m][n][i] + bv, 0.f);
                            rp[m][i] += v * P[(size_t)r * NFEAT + c];
                        }
                    }
                }
            }
            #pragma unroll
            for (int m = 0; m < 4; ++m)
                #pragma unroll
                for (int n = 0; n < 4; ++n)
                    acc[m][n] = (f32x4)(0.f);
        }
    }

    // s0: staging thread partials -> LDS combine
    s0buf[tid] = s0part;

    // s1: reduce rp over the 16 fr lanes
    #pragma unroll
    for (int o = 1; o < 16; o <<= 1) {
        #pragma unroll
        for (int m = 0; m < 4; ++m)
            #pragma unroll
            for (int i = 0; i < 4; ++i)
                rp[m][i] += __shfl_xor(rp[m][i], o);
    }
    if ((lane & 15) == 0) {
        #pragma unroll
        for (int m = 0; m < 4; ++m)
            #pragma unroll
            for (int i = 0; i < 4; ++i)
                atomicAdd(&srow[wr * 64 + m * 16 + fg * 4 + i], rp[m][i]);
    }
    __syncthreads();
    if (tid < 128 && row0 + tid < M) {
        s1g[row0 + tid] = srow[tid];
        s0g[row0 + tid] = s0buf[tid] + s0buf[tid + 128];
    }
}

// ---------------- head GEMM with fused combine ----------------
// logits = (a0*P1 + a1*P2) @ outW + outb ; N = 128
__global__ __launch_bounds__(256, 2) void gemm_head(
    const float* __restrict__ P1, const float* __restrict__ P2,
    const float* __restrict__ alpha,
    const unsigned short* __restrict__ Wh, const unsigned short* __restrict__ Wl,
    const float* __restrict__ bias,
    float* __restrict__ C, int M, int N)
{
    __shared__ unsigned short Ah[128 * 32];
    __shared__ unsigned short Al[128 * 32];
    __shared__ unsigned short Bh[128 * 32];
    __shared__ unsigned short Bl[128 * 32];

    int tid = threadIdx.x;
    int lane = tid & 63;
    int w = tid >> 6;
    int wr = w >> 1, wc = w & 1;
    int row0 = blockIdx.x * 128;
    int fr = lane & 15;
    int fg = lane >> 4;

    int sr = tid & 127;
    int sh = tid >> 7;
    int grow = row0 + sr; if (grow >= M) grow = M - 1;
    int wbase = (((sr >> 4) * 64) + (sh * 2) * 16 + (sr & 15)) * 8;
    int bc = tid >> 1;
    int bk = (tid & 1) * 16;
    int bbase = (((bc >> 4) * 64) + (tid & 1) * 2 * 16 + (bc & 15)) * 8;

    const float* P1row = P1 + (size_t)grow * NFEAT + sh * 16;
    const float* P2row = P2 + (size_t)grow * NFEAT + sh * 16;
    float a0 = alpha[grow], a1 = alpha[M + grow];

    f32x4 acc[4][4];
    #pragma unroll
    for (int m = 0; m < 4; ++m)
        #pragma unroll
        for (int n = 0; n < 4; ++n)
            acc[m][n] = (f32x4)(0.f);

    float uf[16], vf[16];
    us8 bb[4];
    load_a16(P1row, uf);
    load_a16(P2row, vf);
    load_b(Wh + bc * 32 + bk, Wl + bc * 32 + bk, bb);

    for (int it = 0; it < 8; ++it) {
        unsigned short hh[16], ll[16];
        #pragma unroll
        for (int j = 0; j < 16; ++j) f2hilo(a0 * uf[j] + a1 * vf[j], hh[j], ll[j]);
        __syncthreads();
        *(us8*)&Ah[wbase]       = *(us8*)&hh[0];
        *(us8*)&Ah[wbase + 128] = *(us8*)&hh[8];
        *(us8*)&Al[wbase]       = *(us8*)&ll[0];
        *(us8*)&Al[wbase + 128] = *(us8*)&ll[8];
        *(us8*)&Bh[bbase]       = bb[0];
        *(us8*)&Bh[bbase + 128] = bb[1];
        *(us8*)&Bl[bbase]       = bb[2];
        *(us8*)&Bl[bbase + 128] = bb[3];
        __syncthreads();

        if (it + 1 < 8) {
            int kq = it + 1;
            load_a16(P1row + kq * 32, uf);
            load_a16(P2row + kq * 32, vf);
            load_b(Wh + (size_t)kq * 4096 + bc * 32 + bk,
                   Wl + (size_t)kq * 4096 + bc * 32 + bk, bb);
        }

        bf16x8 ahf[4], alf[4], bhf[4], blf[4];
        #pragma unroll
        for (int m = 0; m < 4; ++m) {
            int g = ((wr * 4 + m) * 64 + lane) * 8;
            ahf[m] = *(const bf16x8*)&Ah[g];
            alf[m] = *(const bf16x8*)&Al[g];
        }
        #pragma unroll
        for (int n = 0; n < 4; ++n) {
            int g = ((wc * 4 + n) * 64 + lane) * 8;
            bhf[n] = *(const bf16x8*)&Bh[g];
            blf[n] = *(const bf16x8*)&Bl[g];
        }
        #pragma unroll
        for (int m = 0; m < 4; ++m)
            #pragma unroll
            for (int n = 0; n < 4; ++n) {
                acc[m][n] = __builtin_amdgcn_mfma_f32_16x16x32_bf16(ahf[m], bhf[n], acc[m][n], 0, 0, 0);
                acc[m][n] = __builtin_amdgcn_mfma_f32_16x16x32_bf16(alf[m], bhf[n], acc[m][n], 0, 0, 0);
                acc[m][n] = __builtin_amdgcn_mfma_f32_16x16x32_bf16(ahf[m], blf[n], acc[m][n], 0, 0, 0);
            }
    }

    #pragma unroll
    for (int n = 0; n < 4; ++n) {
        int c = wc * 64 + n * 16 + fr;
        if (c >= N) continue;
        float bv = bias[c];
        #pragma unroll
        for (int m = 0; m < 4; ++m) {
            int rbase = row0 + wr * 64 + m * 16 + fg * 4;
            #pragma unroll
            for (int i = 0; i < 4; ++i) {
                int r = rbase + i;
                if (r < M) C[(size_t)r * N + c] = acc[m][n][i] + bv;
            }
        }
    }
}

extern "C" void kernel_launch(void* const* d_in, const int* in_sizes, int n_in,
                              void* d_out, int out_size, void* d_ws, size_t ws_size,
                              hipStream_t stream)
{
    const float* x_paper    = (const float*)d_in[0];
    const float* emb_author = (const float*)d_in[1];
    const float* W0rp = (const float*)d_in[2];
    const float* b0rp = (const float*)d_in[3];
    const float* W0ra = (const float*)d_in[4];
    const float* b0ra = (const float*)d_in[5];
    const float* W0w  = (const float*)d_in[6];
    const float* W0rev= (const float*)d_in[7];
    const float* W0c  = (const float*)d_in[8];
    const float* W1rp = (const float*)d_in[9];
    const float* b1rp = (const float*)d_in[10];
    const float* W1w  = (const float*)d_in[13];
    const float* W1c  = (const float*)d_in[15];
    const float* outW = (const float*)d_in[16];
    const float* outb = (const float*)d_in[17];
    const int* w_src = (const int*)d_in[18];
    const int* w_dst = (const int*)d_in[19];
    const int* r_src = (const int*)d_in[20];
    const int* r_dst = (const int*)d_in[21];
    const int* c_src = (const int*)d_in[22];
    const int* c_dst = (const int*)d_in[23];

    const int NP = in_sizes[0] / NFEAT;   // 50000
    const int NA = in_sizes[1] / NFEAT;   // 50000
    const int NC = in_sizes[17];          // 128
    const int nEw = in_sizes[18], nEr = in_sizes[20], nEc = in_sizes[22];

    // ---- workspace (~164 MB): 3 big fp32 buffers + planes + CSR ----
    size_t NB = (size_t)(NP > NA ? NP : NA) * NFEAT;
    float* Z0 = (float*)d_ws;
    float* Z1 = Z0 + NB;
    float* Z2 = Z1 + NB;
    float* s0 = Z2 + NB;            // NP
    float* s1 = s0 + NP;            // NP
    unsigned short* Wt = (unsigned short*)(s1 + NP);   // 11 slots x 131072 ushorts
    #define WT_HI(i) (Wt + (size_t)(i) * 131072)
    #define WT_LO(i) (Wt + (size_t)(i) * 131072 + 65536)
    int* degW = (int*)(Wt + 11 * 131072);
    int* degR = degW + NP;
    int* degC = degR + NA;
    int* curW = degC + NP;
    int* curR = curW + NP;
    int* curC = curR + NA;
    int* offW = curC + NP;          // NP+1
    int* offR = offW + NP + 1;      // NA+1
    int* offC = offR + NA + 1;      // NP+1
    int* bsW  = offC + NP + 1;      // 256
    int* bsR  = bsW + 256;
    int* bsC  = bsR + 256;
    int* listW = bsC + 256;         // nEw
    int* listR = listW + nEw;       // nEr
    int* listC = listR + nEr;       // nEc

    float* out   = (float*)d_out;                 // logits [NP, NC]
    float* alpha = out + (size_t)NP * NC;         // [2, NP]

    // ---- CSR build ----
    hipMemsetAsync(degW, 0, (size_t)2 * (NP + NA + NP) * sizeof(int), stream);
    deg_int_kernel<<<(nEw + 255) / 256, 256, 0, stream>>>(w_dst, degW, nEw);
    deg_int_kernel<<<(nEr + 255) / 256, 256, 0, stream>>>(r_dst, degR, nEr);
    deg_int_kernel<<<(nEc + 255) / 256, 256, 0, stream>>>(c_dst, degC, nEc);

    int nbP = (NP + 255) / 256, nbA = (NA + 255) / 256;
    scan_p1<<<nbP, 256, 0, stream>>>(degW, NP, offW, bsW);
    scan_p1<<<nbA, 256, 0, stream>>>(degR, NA, offR, bsR);
    scan_p1<<<nbP, 256, 0, stream>>>(degC, NP, offC, bsC);
    scan_p2<<<3, 256, 0, stream>>>(bsW, nbP, bsR, nbA, bsC, nbP);
    scan_p3<<<nbP, 256, 0, stream>>>(NP, offW, bsW);
    scan_p3<<<nbA, 256, 0, stream>>>(NA, offR, bsR);
    scan_p3<<<nbP, 256, 0, stream>>>(NP, offC, bsC);

    fill_csr_kernel<<<(nEw + 255) / 256, 256, 0, stream>>>(w_src, w_dst, nEw, offW, curW, listW);
    fill_csr_kernel<<<(nEr + 255) / 256, 256, 0, stream>>>(r_src, r_dst, nEr, offR, curR, listR);
    fill_csr_kernel<<<(nEc + 255) / 256, 256, 0, stream>>>(c_src, c_dst, nEc, offC, curC, listC);

    // ---- weight conversion (pre-swizzled planes) ----
    cvt8_kernel<<<dim3(256, 8), 256, 0, stream>>>(W0rp, W0w, W0c, W0ra, W0rev, W1rp, W1w, W1c, Wt);
    cvtfold_kernel<<<dim3(256, 2), 256, 0, stream>>>(W0rp, W0w, W0c, W1rp, W1w, W1c, Wt);
    cvtrect_kernel<<<128, 256, 0, stream>>>(outW, Wt);

    dim3 blk(256);
    dim3 gP(((NP + 127) / 128) * 2);  // flattened: rowblk*2 + colblk
    dim3 gA(((NA + 127) / 128) * 2);
    dim3 g1((NP + 127) / 128);
    int nodeP = (NP + 3) / 4, nodeA = (NA + 3) / 4;

    // --- L0: aggregate raw features, then one fused GEMM per node type ---
    agg_csr_kernel<<<nodeP, blk, 0, stream>>>(emb_author, offW, listW, Z0, 0, 0, NP);  // Mw
    agg_csr_kernel<<<nodeP, blk, 0, stream>>>(x_paper,    offC, listC, Z1, 0, 0, NP);  // Mc
    {   // P1 = relu([Xp|Mw|Mc] @ [W0rp;W0w;W0c] + b0rp) -> Z2
        Seg3 sp = {x_paper, Z0, Z1, WT_HI(0), WT_LO(0), WT_HI(1), WT_LO(1), WT_HI(2), WT_LO(2)};
        gemm_ms<<<gP, blk, 0, stream>>>(sp, 3, b0rp, 1, Z2, NP, NFEAT);
    }
    agg_csr_kernel<<<nodeA, blk, 0, stream>>>(x_paper, offR, listR, Z0, 0, 0, NA);     // Mr
    {   // Au1 = relu([Xa|Mr] @ [W0ra;W0rev] + b0ra) -> Z1
        Seg3 sp = {emb_author, Z0, nullptr, WT_HI(3), WT_LO(3), WT_HI(4), WT_LO(4), nullptr, nullptr};
        gemm_ms<<<gA, blk, 0, stream>>>(sp, 2, b0ra, 1, Z1, NA, NFEAT);
    }

    // --- L1 paper ---
    agg_csr_kernel<<<nodeP, blk, 0, stream>>>(Z1, offW, listW, Z0, 0, 0, NP);          // Mw2 = mean_w(Au1)
    {   // P2pre = [P1|Mw2] @ [W1rp;W1w] + b1rp -> Z1
        Seg3 sp = {Z2, Z0, nullptr, WT_HI(5), WT_LO(5), WT_HI(6), WT_LO(6), nullptr, nullptr};
        gemm_ms<<<gP, blk, 0, stream>>>(sp, 2, b1rp, 0, Z1, NP, NFEAT);
    }
    {   // T = P1 @ W1c -> Z0
        Seg3 sp = {Z2, nullptr, nullptr, WT_HI(7), WT_LO(7), nullptr, nullptr, nullptr, nullptr};
        gemm_ms<<<gP, blk, 0, stream>>>(sp, 1, nullptr, 0, Z0, NP, NFEAT);
    }
    agg_csr_kernel<<<nodeP, blk, 0, stream>>>(Z0, offC, listC, Z1, 1, 1, NP);          // P2 = relu(P2pre + mean_c(T))

    // --- twin path + rowdots ---
    {   // P1t = relu(Xp @ Wc0 + b0rp) -> Z0
        Seg3 sp = {x_paper, nullptr, nullptr, WT_HI(8), WT_LO(8), nullptr, nullptr, nullptr, nullptr};
        gemm_ms<<<gP, blk, 0, stream>>>(sp, 1, b0rp, 1, Z0, NP, NFEAT);
    }
    // s1 = P2 . relu(P1t@Wc1+b1rp) ; s0 = P1 . P1t
    gemm_rowdot_mfma<<<g1, blk, 0, stream>>>(Z0, WT_HI(9), WT_LO(9), b1rp, Z1, Z2, s0, s1, NP);

    // --- summarize + head ---
    alpha_kernel<<<(NP + 255) / 256, blk, 0, stream>>>(s0, s1, alpha, NP);
    gemm_head<<<g1, blk, 0, stream>>>(Z2, Z1, alpha, WT_HI(10), WT_LO(10), outb, out, NP, NC);
}

// Round 13
// 874.377 us; speedup vs baseline: 1.0859x; 1.0859x over previous
//
#include <hip/hip_runtime.h>
#include <hip/hip_bf16.h>

#define NFEAT 256

typedef __attribute__((ext_vector_type(8))) short bf16x8;   // MFMA A/B frag (4 VGPRs)
typedef __attribute__((ext_vector_type(4))) float f32x4;    // MFMA C/D frag
typedef __attribute__((ext_vector_type(8))) unsigned short us8;

__device__ __forceinline__ void f2hilo(float x, unsigned short& h, unsigned short& l) {
    __hip_bfloat16 hb = __float2bfloat16(x);          // RNE
    float hf = __bfloat162float(hb);
    __hip_bfloat16 lb = __float2bfloat16(x - hf);
    h = *reinterpret_cast<unsigned short*>(&hb);
    l = *reinterpret_cast<unsigned short*>(&lb);
}

// LDS granule layout (conflict-free): element (row r, k kk within 32-step) lives at
// granule (r>>4)*64 + (kk>>3)*16 + (r&15), elem kk&7. Wave frag read = 1024B linear.

// ---------------- weight conversion (transposed [N][K] split planes, R8 layout) ----------------
__global__ __launch_bounds__(256) void cvt8_kernel(
    const float* w0, const float* w1, const float* w2, const float* w3,
    const float* w4, const float* w5, const float* w6, const float* w7,
    unsigned short* base)
{
    int wi = blockIdx.y;
    const float* W = (wi==0)?w0:(wi==1)?w1:(wi==2)?w2:(wi==3)?w3:
                     (wi==4)?w4:(wi==5)?w5:(wi==6)?w6:w7;
    int idx = blockIdx.x * 256 + threadIdx.x;     // 0..65535
    int k = idx >> 8, c = idx & 255;
    unsigned short h, l;
    f2hilo(W[idx], h, l);
    unsigned short* Th = base + (size_t)wi * 131072;
    Th[c * 256 + k] = h;
    Th[65536 + c * 256 + k] = l;
}

__global__ __launch_bounds__(256) void cvtfold_kernel(
    const float* a0, const float* a1, const float* a2,
    const float* b0, const float* b1, const float* b2,
    unsigned short* base)
{
    int wi = blockIdx.y;
    int idx = blockIdx.x * 256 + threadIdx.x;
    float v = wi ? (b0[idx] + b1[idx] + b2[idx]) : (a0[idx] + a1[idx] + a2[idx]);
    int k = idx >> 8, c = idx & 255;
    unsigned short h, l;
    f2hilo(v, h, l);
    unsigned short* Th = base + (size_t)(8 + wi) * 131072;
    Th[c * 256 + k] = h;
    Th[65536 + c * 256 + k] = l;
}

__global__ __launch_bounds__(256) void cvtrect_kernel(const float* W, unsigned short* base) {
    int idx = blockIdx.x * 256 + threadIdx.x;     // 0..32767
    if (idx >= 256 * 128) return;
    int k = idx >> 7, c = idx & 127;
    unsigned short h, l;
    f2hilo(W[idx], h, l);
    unsigned short* Th = base + (size_t)10 * 131072;
    Th[c * 256 + k] = h;
    Th[65536 + c * 256 + k] = l;
}

// ---------------- CSR build ----------------
__global__ __launch_bounds__(256) void deg_int_kernel(const int* __restrict__ dst,
                                                      int* __restrict__ deg, int nE) {
    int e = blockIdx.x * 256 + threadIdx.x;
    if (e < nE) atomicAdd(&deg[dst[e]], 1);
}

__global__ __launch_bounds__(256) void scan_p1(const int* __restrict__ deg, int n,
                                               int* __restrict__ off, int* __restrict__ bsum) {
    __shared__ int tmp[256];
    int tid = threadIdx.x;
    int i = blockIdx.x * 256 + tid;
    tmp[tid] = (i < n) ? deg[i] : 0;
    __syncthreads();
    #pragma unroll
    for (int ofs = 1; ofs < 256; ofs <<= 1) {
        int t = (tid >= ofs) ? tmp[tid - ofs] : 0;
        __syncthreads();
        tmp[tid] += t;
        __syncthreads();
    }
    if (i < n) off[i + 1] = tmp[tid];
    if (tid == 255) bsum[blockIdx.x] = tmp[255];
}

__global__ __launch_bounds__(256) void scan_p2(int* __restrict__ bA, int nA,
                                               int* __restrict__ bB, int nB,
                                               int* __restrict__ bC, int nC) {
    int* bs; int nb;
    if (blockIdx.x == 0) { bs = bA; nb = nA; }
    else if (blockIdx.x == 1) { bs = bB; nb = nB; }
    else { bs = bC; nb = nC; }
    __shared__ int tmp[256];
    int tid = threadIdx.x;
    tmp[tid] = (tid < nb) ? bs[tid] : 0;
    __syncthreads();
    #pragma unroll
    for (int ofs = 1; ofs < 256; ofs <<= 1) {
        int t = (tid >= ofs) ? tmp[tid - ofs] : 0;
        __syncthreads();
        tmp[tid] += t;
        __syncthreads();
    }
    if (tid < nb) bs[tid] = tmp[tid];
}

__global__ __launch_bounds__(256) void scan_p3(int n, int* __restrict__ off,
                                               const int* __restrict__ bsum) {
    int i = blockIdx.x * 256 + threadIdx.x;
    if (i == 0) off[0] = 0;
    if (i >= n) return;
    int b = blockIdx.x;
    if (b > 0) off[i + 1] += bsum[b - 1];
}

__global__ __launch_bounds__(256) void fill_csr_kernel(const int* __restrict__ src,
                                                       const int* __restrict__ dst, int nE,
                                                       const int* __restrict__ off,
                                                       int* __restrict__ cursor,
                                                       int* __restrict__ list) {
    int e = blockIdx.x * 256 + threadIdx.x;
    if (e >= nE) return;
    int d = dst[e];
    int pos = atomicAdd(&cursor[d], 1);
    list[off[d] + pos] = src[e];
}

// ---------------- aggregation (gather, no atomics) ----------------
__global__ __launch_bounds__(256) void agg_csr_kernel(const float* __restrict__ T,
                                                      const int* __restrict__ off,
                                                      const int* __restrict__ list,
                                                      float* __restrict__ D,
                                                      int mode_add, int do_relu, int M) {
    int r = blockIdx.x * 4 + (threadIdx.x >> 6);
    if (r >= M) return;
    int lane = threadIdx.x & 63;
    int start = off[r], end = off[r + 1];
    float4 acc = make_float4(0.f, 0.f, 0.f, 0.f);
    for (int e = start; e < end; ++e) {
        int s = list[e];
        float4 v = ((const float4*)(T + (size_t)s * NFEAT))[lane];
        acc.x += v.x; acc.y += v.y; acc.z += v.z; acc.w += v.w;
    }
    int cnt = end - start;
    float inv = (cnt > 0) ? 1.0f / (float)cnt : 0.0f;
    float4 d;
    if (mode_add) {
        d = ((float4*)(D + (size_t)r * NFEAT))[lane];
        d.x += acc.x * inv; d.y += acc.y * inv;
        d.z += acc.z * inv; d.w += acc.w * inv;
    } else {
        d.x = acc.x * inv; d.y = acc.y * inv;
        d.z = acc.z * inv; d.w = acc.w * inv;
    }
    if (do_relu) {
        d.x = fmaxf(d.x, 0.f); d.y = fmaxf(d.y, 0.f);
        d.z = fmaxf(d.z, 0.f); d.w = fmaxf(d.w, 0.f);
    }
    ((float4*)(D + (size_t)r * NFEAT))[lane] = d;
}

// ---------------- alpha ----------------
__global__ __launch_bounds__(256) void alpha_kernel(const float* __restrict__ s0,
                                                    const float* __restrict__ s1,
                                                    float* __restrict__ alpha, int M) {
    int n = blockIdx.x * 256 + threadIdx.x;
    if (n >= M) return;
    float v0 = s0[n], v1 = s1[n];
    float m = fmaxf(v0, v1);
    float e0 = expf(v0 - m), e1 = expf(v1 - m);
    float inv = 1.0f / (e0 + e1);
    alpha[n]     = e0 * inv;
    alpha[M + n] = e1 * inv;
}

// ---------------- multi-segment split-bf16 MFMA GEMM (R8 schedule, granule LDS) ----------------
struct Seg3 {
    const float *A0, *A1, *A2;
    const unsigned short *Wh0, *Wl0, *Wh1, *Wl1, *Wh2, *Wl2;
};

__global__ __launch_bounds__(256, 2) void gemm_ms(
    Seg3 sp, int nseg, const float* __restrict__ bias, int do_relu,
    float* __restrict__ C, int M, int N)
{
    __shared__ unsigned short Ah[128 * 32];   // 8 KB each, granule layout
    __shared__ unsigned short Al[128 * 32];
    __shared__ unsigned short Bh[128 * 32];
    __shared__ unsigned short Bl[128 * 32];

    int tid = threadIdx.x;
    int lane = tid & 63;
    int w = tid >> 6;
    int wr = w >> 1, wc = w & 1;
    int row0 = blockIdx.x * 128, col0 = blockIdx.y * 128;
    int fr = lane & 15;
    int fg = lane >> 4;

    int sr = tid >> 1;            // staging row/col 0..127
    int sk = (tid & 1) * 16;      // k offset 0/16
    int grow = row0 + sr; if (grow >= M) grow = M - 1;
    int gcol = col0 + sr;
    int wbase = ((sr >> 4) * 64 + (sk >> 3) * 16 + (sr & 15)) * 8;  // second 8 elems at +128

    f32x4 acc[4][4];
    #pragma unroll
    for (int m = 0; m < 4; ++m)
        #pragma unroll
        for (int n = 0; n < 4; ++n)
            acc[m][n] = (f32x4)(0.f);

    for (int s = 0; s < 3; ++s) {
        if (s >= nseg) break;
        const float* Xrow = ((s == 0) ? sp.A0 : (s == 1) ? sp.A1 : sp.A2) + (size_t)grow * NFEAT;
        const unsigned short* WhR = ((s == 0) ? sp.Wh0 : (s == 1) ? sp.Wh1 : sp.Wh2) + (size_t)gcol * NFEAT;
        const unsigned short* WlR = ((s == 0) ? sp.Wl0 : (s == 1) ? sp.Wl1 : sp.Wl2) + (size_t)gcol * NFEAT;

        for (int k0 = 0; k0 < NFEAT; k0 += 32) {
            unsigned short hh[16], ll[16];
            #pragma unroll
            for (int q = 0; q < 4; ++q) {
                float4 v = *(const float4*)(Xrow + k0 + sk + q * 4);
                f2hilo(v.x, hh[q*4+0], ll[q*4+0]);
                f2hilo(v.y, hh[q*4+1], ll[q*4+1]);
                f2hilo(v.z, hh[q*4+2], ll[q*4+2]);
                f2hilo(v.w, hh[q*4+3], ll[q*4+3]);
            }
            us8 bh0 = *(const us8*)(WhR + k0 + sk);
            us8 bh1 = *(const us8*)(WhR + k0 + sk + 8);
            us8 bl0 = *(const us8*)(WlR + k0 + sk);
            us8 bl1 = *(const us8*)(WlR + k0 + sk + 8);
            __syncthreads();
            *(us8*)&Ah[wbase]       = *(us8*)&hh[0];
            *(us8*)&Ah[wbase + 128] = *(us8*)&hh[8];
            *(us8*)&Al[wbase]       = *(us8*)&ll[0];
            *(us8*)&Al[wbase + 128] = *(us8*)&ll[8];
            *(us8*)&Bh[wbase]       = bh0;
            *(us8*)&Bh[wbase + 128] = bh1;
            *(us8*)&Bl[wbase]       = bl0;
            *(us8*)&Bl[wbase + 128] = bl1;
            __syncthreads();

            bf16x8 ahf[4], alf[4], bhf[4], blf[4];
            #pragma unroll
            for (int m = 0; m < 4; ++m) {
                int g = ((wr * 4 + m) * 64 + lane) * 8;
                ahf[m] = *(const bf16x8*)&Ah[g];
                alf[m] = *(const bf16x8*)&Al[g];
            }
            #pragma unroll
            for (int n = 0; n < 4; ++n) {
                int g = ((wc * 4 + n) * 64 + lane) * 8;
                bhf[n] = *(const bf16x8*)&Bh[g];
                blf[n] = *(const bf16x8*)&Bl[g];
            }
            #pragma unroll
            for (int m = 0; m < 4; ++m)
                #pragma unroll
                for (int n = 0; n < 4; ++n) {
                    acc[m][n] = __builtin_amdgcn_mfma_f32_16x16x32_bf16(ahf[m], bhf[n], acc[m][n], 0, 0, 0);
                    acc[m][n] = __builtin_amdgcn_mfma_f32_16x16x32_bf16(alf[m], bhf[n], acc[m][n], 0, 0, 0);
                    acc[m][n] = __builtin_amdgcn_mfma_f32_16x16x32_bf16(ahf[m], blf[n], acc[m][n], 0, 0, 0);
                }
        }
    }

    #pragma unroll
    for (int n = 0; n < 4; ++n) {
        int c = col0 + wc * 64 + n * 16 + fr;
        float bv = bias ? bias[c] : 0.f;
        #pragma unroll
        for (int m = 0; m < 4; ++m) {
            int rbase = row0 + wr * 64 + m * 16 + fg * 4;
            #pragma unroll
            for (int i = 0; i < 4; ++i) {
                int r = rbase + i;
                if (r < M) {
                    float v = acc[m][n][i] + bv;
                    if (do_relu) v = fmaxf(v, 0.f);
                    C[(size_t)r * N + c] = v;
                }
            }
        }
    }
}

// ---------------- twin L1 + both rowdots, fused (R8 schedule, granule LDS) ----------------
// s1[r] = dot( relu(X[r]@W + bias), P[r] );  s0[r] = dot(X[r], Q[r])
__global__ __launch_bounds__(256, 2) void gemm_rowdot_mfma(
    const float* __restrict__ X,
    const unsigned short* __restrict__ Wh, const unsigned short* __restrict__ Wl,
    const float* __restrict__ bias,
    const float* __restrict__ P, const float* __restrict__ Q,
    float* __restrict__ s0g, float* __restrict__ s1g, int M)
{
    __shared__ unsigned short Ah[128 * 32];
    __shared__ unsigned short Al[128 * 32];
    __shared__ unsigned short Bh[128 * 32];
    __shared__ unsigned short Bl[128 * 32];
    __shared__ float srow[128];
    __shared__ float s0buf[256];

    int tid = threadIdx.x;
    int lane = tid & 63;
    int w = tid >> 6;
    int wr = w >> 1, wc = w & 1;
    int row0 = blockIdx.x * 128;
    int fr = lane & 15;
    int fg = lane >> 4;

    int sr = tid >> 1;
    int sk = (tid & 1) * 16;
    int grow = row0 + sr; if (grow >= M) grow = M - 1;
    int wbase = ((sr >> 4) * 64 + (sk >> 3) * 16 + (sr & 15)) * 8;

    if (tid < 128) srow[tid] = 0.f;
    float s0part = 0.f;

    const float* Xrow = X + (size_t)grow * NFEAT;
    const float* Qrow = Q + (size_t)grow * NFEAT;

    float rp[4][4];
    #pragma unroll
    for (int m = 0; m < 4; ++m)
        #pragma unroll
        for (int i = 0; i < 4; ++i) rp[m][i] = 0.f;

    for (int ct = 0; ct < 2; ++ct) {
        int col0 = ct * 128;
        const unsigned short* WhR = Wh + (size_t)(col0 + sr) * NFEAT;
        const unsigned short* WlR = Wl + (size_t)(col0 + sr) * NFEAT;

        f32x4 acc[4][4];
        #pragma unroll
        for (int m = 0; m < 4; ++m)
            #pragma unroll
            for (int n = 0; n < 4; ++n)
                acc[m][n] = (f32x4)(0.f);

        for (int k0 = 0; k0 < NFEAT; k0 += 32) {
            unsigned short hh[16], ll[16];
            #pragma unroll
            for (int q = 0; q < 4; ++q) {
                float4 v = *(const float4*)(Xrow + k0 + sk + q * 4);
                if (ct == 0) {
                    float4 qv = *(const float4*)(Qrow + k0 + sk + q * 4);
                    s0part += v.x * qv.x + v.y * qv.y + v.z * qv.z + v.w * qv.w;
                }
                f2hilo(v.x, hh[q*4+0], ll[q*4+0]);
                f2hilo(v.y, hh[q*4+1], ll[q*4+1]);
                f2hilo(v.z, hh[q*4+2], ll[q*4+2]);
                f2hilo(v.w, hh[q*4+3], ll[q*4+3]);
            }
            us8 bh0 = *(const us8*)(WhR + k0 + sk);
            us8 bh1 = *(const us8*)(WhR + k0 + sk + 8);
            us8 bl0 = *(const us8*)(WlR + k0 + sk);
            us8 bl1 = *(const us8*)(WlR + k0 + sk + 8);
            __syncthreads();
            *(us8*)&Ah[wbase]       = *(us8*)&hh[0];
            *(us8*)&Ah[wbase + 128] = *(us8*)&hh[8];
            *(us8*)&Al[wbase]       = *(us8*)&ll[0];
            *(us8*)&Al[wbase + 128] = *(us8*)&ll[8];
            *(us8*)&Bh[wbase]       = bh0;
            *(us8*)&Bh[wbase + 128] = bh1;
            *(us8*)&Bl[wbase]       = bl0;
            *(us8*)&Bl[wbase + 128] = bl1;
            __syncthreads();

            bf16x8 ahf[4], alf[4], bhf[4], blf[4];
            #pragma unroll
            for (int m = 0; m < 4; ++m) {
                int g = ((wr * 4 + m) * 64 + lane) * 8;
                ahf[m] = *(const bf16x8*)&Ah[g];
                alf[m] = *(const bf16x8*)&Al[g];
            }
            #pragma unroll
            for (int n = 0; n < 4; ++n) {
                int g = ((wc * 4 + n) * 64 + lane) * 8;
                bhf[n] = *(const bf16x8*)&Bh[g];
                blf[n] = *(const bf16x8*)&Bl[g];
            }
            #pragma unroll
            for (int m = 0; m < 4; ++m)
                #pragma unroll
                for (int n = 0; n < 4; ++n) {
                    acc[m][n] = __builtin_amdgcn_mfma_f32_16x16x32_bf16(ahf[m], bhf[n], acc[m][n], 0, 0, 0);
                    acc[m][n] = __builtin_amdgcn_mfma_f32_16x16x32_bf16(alf[m], bhf[n], acc[m][n], 0, 0, 0);
                    acc[m][n] = __builtin_amdgcn_mfma_f32_16x16x32_bf16(ahf[m], blf[n], acc[m][n], 0, 0, 0);
                }
        }

        // fold this col-half into the row dot-products
        #pragma unroll
        for (int n = 0; n < 4; ++n) {
            int c = col0 + wc * 64 + n * 16 + fr;
            float bv = bias[c];
            #pragma unroll
            for (int m = 0; m < 4; ++m) {
                #pragma unroll
                for (int i = 0; i < 4; ++i) {
                    int r = row0 + wr * 64 + m * 16 + fg * 4 + i;
                    if (r < M) {
                        float v = fmaxf(acc[m][n][i] + bv, 0.f);
                        rp[m][i] += v * P[(size_t)r * NFEAT + c];
                    }
                }
            }
        }
    }

    // s0: staging thread partials -> LDS combine (halves live in adjacent threads)
    s0buf[tid] = s0part;

    // s1: reduce rp over the 16 fr lanes
    #pragma unroll
    for (int o = 1; o < 16; o <<= 1) {
        #pragma unroll
        for (int m = 0; m < 4; ++m)
            #pragma unroll
            for (int i = 0; i < 4; ++i)
                rp[m][i] += __shfl_xor(rp[m][i], o);
    }
    if ((lane & 15) == 0) {
        #pragma unroll
        for (int m = 0; m < 4; ++m)
            #pragma unroll
            for (int i = 0; i < 4; ++i)
                atomicAdd(&srow[wr * 64 + m * 16 + fg * 4 + i], rp[m][i]);
    }
    __syncthreads();
    if (tid < 128 && row0 + tid < M) {
        s1g[row0 + tid] = srow[tid];
        s0g[row0 + tid] = s0buf[tid * 2] + s0buf[tid * 2 + 1];
    }
}

// ---------------- head GEMM with fused combine (R8 schedule, granule LDS) ----------------
// logits = (a0*P1 + a1*P2) @ outW + outb ; N = 128
__global__ __launch_bounds__(256, 2) void gemm_head(
    const float* __restrict__ P1, const float* __restrict__ P2,
    const float* __restrict__ alpha,
    const unsigned short* __restrict__ Wh, const unsigned short* __restrict__ Wl,
    const float* __restrict__ bias,
    float* __restrict__ C, int M, int N)
{
    __shared__ unsigned short Ah[128 * 32];
    __shared__ unsigned short Al[128 * 32];
    __shared__ unsigned short Bh[128 * 32];
    __shared__ unsigned short Bl[128 * 32];

    int tid = threadIdx.x;
    int lane = tid & 63;
    int w = tid >> 6;
    int wr = w >> 1, wc = w & 1;
    int row0 = blockIdx.x * 128;
    int fr = lane & 15;
    int fg = lane >> 4;

    int sr = tid >> 1;
    int sk = (tid & 1) * 16;
    int grow = row0 + sr; if (grow >= M) grow = M - 1;
    int wbase = ((sr >> 4) * 64 + (sk >> 3) * 16 + (sr & 15)) * 8;

    const float* P1row = P1 + (size_t)grow * NFEAT;
    const float* P2row = P2 + (size_t)grow * NFEAT;
    float a0 = alpha[grow], a1 = alpha[M + grow];
    const unsigned short* WhR = Wh + (size_t)sr * NFEAT;
    const unsigned short* WlR = Wl + (size_t)sr * NFEAT;

    f32x4 acc[4][4];
    #pragma unroll
    for (int m = 0; m < 4; ++m)
        #pragma unroll
        for (int n = 0; n < 4; ++n)
            acc[m][n] = (f32x4)(0.f);

    for (int k0 = 0; k0 < NFEAT; k0 += 32) {
        unsigned short hh[16], ll[16];
        #pragma unroll
        for (int q = 0; q < 4; ++q) {
            float4 u = *(const float4*)(P1row + k0 + sk + q * 4);
            float4 v = *(const float4*)(P2row + k0 + sk + q * 4);
            float4 x = make_float4(a0*u.x + a1*v.x, a0*u.y + a1*v.y,
                                   a0*u.z + a1*v.z, a0*u.w + a1*v.w);
            f2hilo(x.x, hh[q*4+0], ll[q*4+0]);
            f2hilo(x.y, hh[q*4+1], ll[q*4+1]);
            f2hilo(x.z, hh[q*4+2], ll[q*4+2]);
            f2hilo(x.w, hh[q*4+3], ll[q*4+3]);
        }
        us8 bh0 = *(const us8*)(WhR + k0 + sk);
        us8 bh1 = *(const us8*)(WhR + k0 + sk + 8);
        us8 bl0 = *(const us8*)(WlR + k0 + sk);
        us8 bl1 = *(const us8*)(WlR + k0 + sk + 8);
        __syncthreads();
        *(us8*)&Ah[wbase]       = *(us8*)&hh[0];
        *(us8*)&Ah[wbase + 128] = *(us8*)&hh[8];
        *(us8*)&Al[wbase]       = *(us8*)&ll[0];
        *(us8*)&Al[wbase + 128] = *(us8*)&ll[8];
        *(us8*)&Bh[wbase]       = bh0;
        *(us8*)&Bh[wbase + 128] = bh1;
        *(us8*)&Bl[wbase]       = bl0;
        *(us8*)&Bl[wbase + 128] = bl1;
        __syncthreads();

        bf16x8 ahf[4], alf[4], bhf[4], blf[4];
        #pragma unroll
        for (int m = 0; m < 4; ++m) {
            int g = ((wr * 4 + m) * 64 + lane) * 8;
            ahf[m] = *(const bf16x8*)&Ah[g];
            alf[m] = *(const bf16x8*)&Al[g];
        }
        #pragma unroll
        for (int n = 0; n < 4; ++n) {
            int g = ((wc * 4 + n) * 64 + lane) * 8;
            bhf[n] = *(const bf16x8*)&Bh[g];
            blf[n] = *(const bf16x8*)&Bl[g];
        }
        #pragma unroll
        for (int m = 0; m < 4; ++m)
            #pragma unroll
            for (int n = 0; n < 4; ++n) {
                acc[m][n] = __builtin_amdgcn_mfma_f32_16x16x32_bf16(ahf[m], bhf[n], acc[m][n], 0, 0, 0);
                acc[m][n] = __builtin_amdgcn_mfma_f32_16x16x32_bf16(alf[m], bhf[n], acc[m][n], 0, 0, 0);
                acc[m][n] = __builtin_amdgcn_mfma_f32_16x16x32_bf16(ahf[m], blf[n], acc[m][n], 0, 0, 0);
            }
    }

    #pragma unroll
    for (int n = 0; n < 4; ++n) {
        int c = wc * 64 + n * 16 + fr;
        if (c >= N) continue;
        float bv = bias[c];
        #pragma unroll
        for (int m = 0; m < 4; ++m) {
            int rbase = row0 + wr * 64 + m * 16 + fg * 4;
            #pragma unroll
            for (int i = 0; i < 4; ++i) {
                int r = rbase + i;
                if (r < M) C[(size_t)r * N + c] = acc[m][n][i] + bv;
            }
        }
    }
}

extern "C" void kernel_launch(void* const* d_in, const int* in_sizes, int n_in,
                              void* d_out, int out_size, void* d_ws, size_t ws_size,
                              hipStream_t stream)
{
    const float* x_paper    = (const float*)d_in[0];
    const float* emb_author = (const float*)d_in[1];
    const float* W0rp = (const float*)d_in[2];
    const float* b0rp = (const float*)d_in[3];
    const float* W0ra = (const float*)d_in[4];
    const float* b0ra = (const float*)d_in[5];
    const float* W0w  = (const float*)d_in[6];
    const float* W0rev= (const float*)d_in[7];
    const float* W0c  = (const float*)d_in[8];
    const float* W1rp = (const float*)d_in[9];
    const float* b1rp = (const float*)d_in[10];
    const float* W1w  = (const float*)d_in[13];
    const float* W1c  = (const float*)d_in[15];
    const float* outW = (const float*)d_in[16];
    const float* outb = (const float*)d_in[17];
    const int* w_src = (const int*)d_in[18];
    const int* w_dst = (const int*)d_in[19];
    const int* r_src = (const int*)d_in[20];
    const int* r_dst = (const int*)d_in[21];
    const int* c_src = (const int*)d_in[22];
    const int* c_dst = (const int*)d_in[23];

    const int NP = in_sizes[0] / NFEAT;   // 50000
    const int NA = in_sizes[1] / NFEAT;   // 50000
    const int NC = in_sizes[17];          // 128
    const int nEw = in_sizes[18], nEr = in_sizes[20], nEc = in_sizes[22];

    // ---- workspace (~164 MB): 3 big fp32 buffers + planes + CSR ----
    size_t NB = (size_t)(NP > NA ? NP : NA) * NFEAT;
    float* Z0 = (float*)d_ws;
    float* Z1 = Z0 + NB;
    float* Z2 = Z1 + NB;
    float* s0 = Z2 + NB;            // NP
    float* s1 = s0 + NP;            // NP
    unsigned short* Wt = (unsigned short*)(s1 + NP);   // 11 slots x 131072 ushorts
    #define WT_HI(i) (Wt + (size_t)(i) * 131072)
    #define WT_LO(i) (Wt + (size_t)(i) * 131072 + 65536)
    int* degW = (int*)(Wt + 11 * 131072);
    int* degR = degW + NP;
    int* degC = degR + NA;
    int* curW = degC + NP;
    int* curR = curW + NP;
    int* curC = curR + NA;
    int* offW = curC + NP;          // NP+1
    int* offR = offW + NP + 1;      // NA+1
    int* offC = offR + NA + 1;      // NP+1
    int* bsW  = offC + NP + 1;      // 256
    int* bsR  = bsW + 256;
    int* bsC  = bsR + 256;
    int* listW = bsC + 256;         // nEw
    int* listR = listW + nEw;       // nEr
    int* listC = listR + nEr;       // nEc

    float* out   = (float*)d_out;                 // logits [NP, NC]
    float* alpha = out + (size_t)NP * NC;         // [2, NP]

    // ---- CSR build ----
    hipMemsetAsync(degW, 0, (size_t)2 * (NP + NA + NP) * sizeof(int), stream);
    deg_int_kernel<<<(nEw + 255) / 256, 256, 0, stream>>>(w_dst, degW, nEw);
    deg_int_kernel<<<(nEr + 255) / 256, 256, 0, stream>>>(r_dst, degR, nEr);
    deg_int_kernel<<<(nEc + 255) / 256, 256, 0, stream>>>(c_dst, degC, nEc);

    int nbP = (NP + 255) / 256, nbA = (NA + 255) / 256;
    scan_p1<<<nbP, 256, 0, stream>>>(degW, NP, offW, bsW);
    scan_p1<<<nbA, 256, 0, stream>>>(degR, NA, offR, bsR);
    scan_p1<<<nbP, 256, 0, stream>>>(degC, NP, offC, bsC);
    scan_p2<<<3, 256, 0, stream>>>(bsW, nbP, bsR, nbA, bsC, nbP);
    scan_p3<<<nbP, 256, 0, stream>>>(NP, offW, bsW);
    scan_p3<<<nbA, 256, 0, stream>>>(NA, offR, bsR);
    scan_p3<<<nbP, 256, 0, stream>>>(NP, offC, bsC);

    fill_csr_kernel<<<(nEw + 255) / 256, 256, 0, stream>>>(w_src, w_dst, nEw, offW, curW, listW);
    fill_csr_kernel<<<(nEr + 255) / 256, 256, 0, stream>>>(r_src, r_dst, nEr, offR, curR, listR);
    fill_csr_kernel<<<(nEc + 255) / 256, 256, 0, stream>>>(c_src, c_dst, nEc, offC, curC, listC);

    // ---- weight conversion ([N][K] split planes) ----
    cvt8_kernel<<<dim3(256, 8), 256, 0, stream>>>(W0rp, W0w, W0c, W0ra, W0rev, W1rp, W1w, W1c, Wt);
    cvtfold_kernel<<<dim3(256, 2), 256, 0, stream>>>(W0rp, W0w, W0c, W1rp, W1w, W1c, Wt);
    cvtrect_kernel<<<128, 256, 0, stream>>>(outW, Wt);

    dim3 blk(256);
    dim3 gP((NP + 127) / 128, 2);     // N=256
    dim3 gA((NA + 127) / 128, 2);
    dim3 g1((NP + 127) / 128);
    int nodeP = (NP + 3) / 4, nodeA = (NA + 3) / 4;

    // --- L0: aggregate raw features, then one fused GEMM per node type ---
    agg_csr_kernel<<<nodeP, blk, 0, stream>>>(emb_author, offW, listW, Z0, 0, 0, NP);  // Mw
    agg_csr_kernel<<<nodeP, blk, 0, stream>>>(x_paper,    offC, listC, Z1, 0, 0, NP);  // Mc
    {   // P1 = relu([Xp|Mw|Mc] @ [W0rp;W0w;W0c] + b0rp) -> Z2
        Seg3 sp = {x_paper, Z0, Z1, WT_HI(0), WT_LO(0), WT_HI(1), WT_LO(1), WT_HI(2), WT_LO(2)};
        gemm_ms<<<gP, blk, 0, stream>>>(sp, 3, b0rp, 1, Z2, NP, NFEAT);
    }
    agg_csr_kernel<<<nodeA, blk, 0, stream>>>(x_paper, offR, listR, Z0, 0, 0, NA);     // Mr
    {   // Au1 = relu([Xa|Mr] @ [W0ra;W0rev] + b0ra) -> Z1
        Seg3 sp = {emb_author, Z0, nullptr, WT_HI(3), WT_LO(3), WT_HI(4), WT_LO(4), nullptr, nullptr};
        gemm_ms<<<gA, blk, 0, stream>>>(sp, 2, b0ra, 1, Z1, NA, NFEAT);
    }

    // --- L1 paper ---
    agg_csr_kernel<<<nodeP, blk, 0, stream>>>(Z1, offW, listW, Z0, 0, 0, NP);          // Mw2 = mean_w(Au1)
    {   // P2pre = [P1|Mw2] @ [W1rp;W1w] + b1rp -> Z1
        Seg3 sp = {Z2, Z0, nullptr, WT_HI(5), WT_LO(5), WT_HI(6), WT_LO(6), nullptr, nullptr};
        gemm_ms<<<gP, blk, 0, stream>>>(sp, 2, b1rp, 0, Z1, NP, NFEAT);
    }
    {   // T = P1 @ W1c -> Z0
        Seg3 sp = {Z2, nullptr, nullptr, WT_HI(7), WT_LO(7), nullptr, nullptr, nullptr, nullptr};
        gemm_ms<<<gP, blk, 0, stream>>>(sp, 1, nullptr, 0, Z0, NP, NFEAT);
    }
    agg_csr_kernel<<<nodeP, blk, 0, stream>>>(Z0, offC, listC, Z1, 1, 1, NP);          // P2 = relu(P2pre + mean_c(T))

    // --- twin path + rowdots ---
    {   // P1t = relu(Xp @ Wc0 + b0rp) -> Z0
        Seg3 sp = {x_paper, nullptr, nullptr, WT_HI(8), WT_LO(8), nullptr, nullptr, nullptr, nullptr};
        gemm_ms<<<gP, blk, 0, stream>>>(sp, 1, b0rp, 1, Z0, NP, NFEAT);
    }
    // s1 = P2 . relu(P1t@Wc1+b1rp) ; s0 = P1 . P1t
    gemm_rowdot_mfma<<<g1, blk, 0, stream>>>(Z0, WT_HI(9), WT_LO(9), b1rp, Z1, Z2, s0, s1, NP);

    // --- summarize + head ---
    alpha_kernel<<<(NP + 255) / 256, blk, 0, stream>>>(s0, s1, alpha, NP);
    gemm_head<<<g1, blk, 0, stream>>>(Z2, Z1, alpha, WT_HI(10), WT_LO(10), outb, out, NP, NC);
}